// Round 14
// baseline (961.197 us; speedup 1.0000x reference)
//
#include <hip/hip_runtime.h>
#include <math.h>

// BiometricLSTM: 2-layer LSTM, B=512, T=2048, I=3, H=64, fp32 in/out. Output = final h2 (B,64).
//
// R31: R30 (best, 931.2 us) + ONE variable: L1 body reorder
//   {gates -> pI -> tail -> write}  ==>  {gates -> tail -> write -> pI}.
// Theory: a wave issues in PROGRAM ORDER across pipes. L1's tail (sel4 of the
// gate accs) could not issue until all 16 MFMAs (8 gate + 8 pI) cleared the
// issue slot — ~32-64cy of delay on L1's path to the barrier for pI work whose
// deadline is NEXT iteration. L1 (16 MFMA) arrives last at every one of 2050
// barriers, so its arrival sets T_iter. Moving the pI MFMAs after the h2 write
// lets them execute during the lgkm-drain + barrier wait (dead time). They are
// register-only (b0/b1 pre-loaded, accQ dest) — no LDS interaction, so the
// lds_barrier's lgkmcnt(0) is unaffected. Same trick as R20's gates-before-pI
// (-8.5%), applied inside L1. Zero arithmetic change; absmax 4.88e-4 canary.
// R30 recap (all kept): f-first MFMA order {f,i,g,o}; fused tanh muls
// (m2iv/m2ov off-chain, fmaf on-chain); log2e-prescaled weights (bare v_exp2);
// L1 read-window sel4 hoists; 2-level sel4 tree; split waves L0=Whh0 8 MFMA /
// L1=Whh1+Wih1 lag-2; pI in regs accQ[2][4] (write@sub, read@sub^1); no pIbuf;
// LDS 2560B, 0 conflicts; unroll-2 compile-time parity; M=4 replicated rows;
// quad-selected update; HSTR=80; z-chained MFMA pairs bias-in-C; x prefetch
// depth-1; lds_barrier (lgkmcnt-only drain); setprio(1) on L0; f16 weights/h +
// f32 accum.
// Parities: h1[t]@t&1; h2[t]@t&1; accQ write@sub / read@sub^1.

typedef _Float16 half8 __attribute__((ext_vector_type(8)));
typedef float    f32x4 __attribute__((ext_vector_type(4)));

constexpr int TT = 2048;
constexpr int HSTR = 80;   // h row stride in halves (160 B)

#define LOG2E  1.44269504088896340736f
#define LOG2E2 2.88539008177792681472f

// y = x*log2e applied upstream: sigmoid(x) = 1/(1+2^-y)
__device__ __forceinline__ float sig_p(float y) {
    return __builtin_amdgcn_rcpf(1.0f + __builtin_amdgcn_exp2f(-y));
}
// y = x*2log2e applied upstream: r = 1/(2^y+1); tanh(x) = 1 - 2r
__device__ __forceinline__ float tanh_r(float y) {
    return __builtin_amdgcn_rcpf(__builtin_amdgcn_exp2f(y) + 1.0f);
}
// select component q (lane's quad) from an f32x4 accumulator — 2-level tree
__device__ __forceinline__ float sel4(f32x4 v, int q) {
    float lo = (q & 1) ? v[1] : v[0];
    float hi = (q & 1) ? v[3] : v[2];
    return (q & 2) ? hi : lo;
}

// Barrier with LDS-only drain: s_waitcnt lgkmcnt(0) + s_barrier.
// Does NOT drain vmcnt — in-flight global x-prefetch loads stay in flight.
__device__ __forceinline__ void lds_barrier() {
    __builtin_amdgcn_sched_barrier(0);
    asm volatile("s_waitcnt lgkmcnt(0)" ::: "memory");
    __builtin_amdgcn_s_barrier();
    __builtin_amdgcn_sched_barrier(0);
}

__global__ __launch_bounds__(512) void lstm2_fused(
    const float* __restrict__ x,
    const float* __restrict__ Wih0, const float* __restrict__ Whh0,
    const float* __restrict__ bih0, const float* __restrict__ bhh0,
    const float* __restrict__ Wih1, const float* __restrict__ Whh1,
    const float* __restrict__ bih1, const float* __restrict__ bhh1,
    float* __restrict__ out)
{
    __shared__ __align__(16) _Float16 h1a[2][4 * HSTR];   // [parity][seq*HSTR + elem]
    __shared__ __align__(16) _Float16 h2a[2][4 * HSTR];

    const int tid  = threadIdx.x;
    const int lane = tid & 63;
    const int wid  = tid >> 6;
    const int quad = lane >> 4;
    const int l16  = lane & 15;
    const bool isL1 = (wid >= 4);
    const int col  = (wid & 3) * 16 + l16;   // gate-elem column this lane owns per class

    // ---- zero h double-buffers ----
    for (int i = tid; i < 2 * 4 * HSTR; i += 512) {
        ((_Float16*)h1a)[i] = (_Float16)0.0f;
        ((_Float16*)h2a)[i] = (_Float16)0.0f;
    }

    // ---- weights (B-frags, f16), log2e-prescaled per gate class ----
    // class c: 0=i 1=f 2=g 3=o; scale = log2e (sigmoid) or 2*log2e (tanh g)
    half8 wA[4][2];      // L0 waves: Whh0 | L1 waves: Whh1
    half8 wB[4][2];      // L1 waves only: Wih1
    f32x4 cbias[4];      // bias splat (prescaled), MFMA C-init
    float wxa[4], wxb[4], wxc[4];            // L0 only (prescaled)
    #pragma unroll
    for (int c = 0; c < 4; ++c) {
        const int row = c * 64 + col;
        const float sc = (c == 2) ? LOG2E2 : LOG2E;
        if (!isL1) {
            #pragma unroll
            for (int f = 0; f < 2; ++f) {
                const float* p = Whh0 + (size_t)row * 64 + f * 32 + quad * 8;
                half8 h;
                #pragma unroll
                for (int u = 0; u < 8; ++u) h[u] = (_Float16)(p[u] * sc);
                wA[c][f] = h;
            }
            const float b = (bih0[row] + bhh0[row]) * sc;
            cbias[c] = f32x4{b, b, b, b};
            wxa[c] = Wih0[row*3+0] * sc;
            wxb[c] = Wih0[row*3+1] * sc;
            wxc[c] = Wih0[row*3+2] * sc;
        } else {
            #pragma unroll
            for (int f = 0; f < 2; ++f) {
                const float* p = Whh1 + (size_t)row * 64 + f * 32 + quad * 8;
                half8 h;
                #pragma unroll
                for (int u = 0; u < 8; ++u) h[u] = (_Float16)(p[u] * sc);
                wA[c][f] = h;
                const float* q = Wih1 + (size_t)row * 64 + f * 32 + quad * 8;
                half8 g;
                #pragma unroll
                for (int u = 0; u < 8; ++u) g[u] = (_Float16)(q[u] * sc);
                wB[c][f] = g;
            }
            const float b = (bih1[row] + bhh1[row]) * sc;
            cbias[c] = f32x4{b, b, b, b};
        }
    }

    // ---- x prefetch (L0 waves), depth 1: this lane's seq = quad ----
    const float* xq = x + (size_t)(blockIdx.x * 4 + quad) * TT * 3;
    float xn0 = 0.f, xn1 = 0.f, xn2 = 0.f;
    if (!isL1) { xn0 = xq[0]; xn1 = xq[1]; xn2 = xq[2]; }

    const f32x4 Z = {0.f, 0.f, 0.f, 0.f};
    float cst = 0.0f;    // cell state (layer per role, seq=quad, elem=col)

    // L1: pI double-buffer in registers; accQ[sub] written at parity sub,
    // read at sub^1. Indices are compile-time after the unroll (rule #20).
    f32x4 accQ[2][4];
    #pragma unroll
    for (int s = 0; s < 2; ++s)
        #pragma unroll
        for (int c = 0; c < 4; ++c) accQ[s][c] = Z;

    // protect the h1-recurrence wave at issue-contention points (R29: neutral,
    // kept — no cost).
    if (!isL1) __builtin_amdgcn_s_setprio(1);

    __syncthreads();   // init barrier: full drain fine here (once)

    // MFMA issue order: f first (c-update consumes fv first), o last.
    const int ORD[4] = {1, 0, 2, 3};

    // iter it = 0 .. TT+1 in unrolled pairs (cur/prev compile-time).
    // L0: step it (it<TT).  L1: gates for step it-2 (it>=2) + pI(it-1) (1<=it<=TT).
    // ONE lds_barrier per iteration.
    for (int bt = 0; bt <= TT + 1; bt += 2) {
        #pragma unroll
        for (int sub = 0; sub < 2; ++sub) {
            const int it   = bt + sub;
            const int cur  = sub;        // bt even => it&1 == sub
            const int prev = sub ^ 1;

            if (!isL1) {
                if (it < TT) {
                    // A-frags: h1[it-1] (parity prev), replicated rows
                    const _Float16* hb = h1a[prev] + (l16 & 3) * HSTR + quad * 8;
                    half8 a0 = *(const half8*)hb;
                    half8 a1 = *(const half8*)(hb + 32);

                    // x-projection (prescaled): fills the ds_read window.
                    const float x0 = xn0, x1 = xn1, x2 = xn2;
                    float xp0 = fmaf(wxa[0], x0, fmaf(wxb[0], x1, wxc[0] * x2));
                    float xp1 = fmaf(wxa[1], x0, fmaf(wxb[1], x1, wxc[1] * x2));
                    float xp2 = fmaf(wxa[2], x0, fmaf(wxb[2], x1, wxc[2] * x2));
                    float xp3 = fmaf(wxa[3], x0, fmaf(wxb[3], x1, wxc[3] * x2));
                    const int nt = (it + 1 < TT) ? it + 1 : TT - 1;
                    const float* np = xq + nt * 3;
                    xn0 = np[0]; xn1 = np[1]; xn2 = np[2];

                    // L0 gates: Whh0 . h1[it-1] + bias (in C), f-class first.
                    f32x4 acc[4];
                    #pragma unroll
                    for (int k = 0; k < 4; ++k) {
                        const int c = ORD[k];
                        f32x4 z = cbias[c];
                        z = __builtin_amdgcn_mfma_f32_16x16x32_f16(a0, wA[c][0], z, 0, 0, 0);
                        z = __builtin_amdgcn_mfma_f32_16x16x32_f16(a1, wA[c][1], z, 0, 0, 0);
                        acc[c] = z;
                    }
                    float pf = sel4(acc[1], quad) + xp1;
                    float pi = sel4(acc[0], quad) + xp0;
                    float pg = sel4(acc[2], quad) + xp2;
                    float po = sel4(acc[3], quad) + xp3;
                    float fv = sig_p(pf), iv = sig_p(pi), ov = sig_p(po);
                    float rg = tanh_r(pg);
                    float m2iv = -2.0f * iv;                 // off-chain
                    float igv = fmaf(m2iv, rg, iv);          // iv*tanh(g), 1 dep
                    cst = fmaf(fv, cst, igv);
                    float m2ov = -2.0f * ov;                 // off-chain (c runs)
                    float rh = tanh_r(cst * LOG2E2);
                    float hv = fmaf(m2ov, rh, ov);           // ov*tanh(c), 1 dep
                    h1a[cur][quad * HSTR + col] = (_Float16)hv;   // h1[it]
                }
            } else {
                const bool doG = (it >= 2);             // gates for step it-2
                const bool doQ = (it >= 1 && it <= TT); // pI(it-1) for next iter

                // ds_reads first (both frag sets issue together)
                half8 a2, a3, b0, b1;
                if (doG) {
                    const _Float16* hb2 = h2a[prev] + (l16 & 3) * HSTR + quad * 8;
                    a2 = *(const half8*)hb2;
                    a3 = *(const half8*)(hb2 + 32);
                }
                if (doQ) {
                    const _Float16* hb1 = h1a[prev] + (l16 & 3) * HSTR + quad * 8;
                    b0 = *(const half8*)hb1;
                    b1 = *(const half8*)(hb1 + 32);
                }

                // read-window fill: pI(it-2) quad-selects (off the tail chain)
                float qp0, qp1, qp2, qp3;
                if (doG) {
                    qp0 = sel4(accQ[prev][0], quad);
                    qp1 = sel4(accQ[prev][1], quad);
                    qp2 = sel4(accQ[prev][2], quad);
                    qp3 = sel4(accQ[prev][3], quad);
                }

                // gate MFMAs issue first, f-class first — then TAIL, then pI.
                f32x4 acc[4];
                if (doG) {
                    #pragma unroll
                    for (int k = 0; k < 4; ++k) {
                        const int c = ORD[k];
                        f32x4 z = cbias[c];
                        z = __builtin_amdgcn_mfma_f32_16x16x32_f16(a2, wA[c][0], z, 0, 0, 0);
                        z = __builtin_amdgcn_mfma_f32_16x16x32_f16(a3, wA[c][1], z, 0, 0, 0);
                        acc[c] = z;
                    }
                    // R31: tail directly after gate MFMAs — no longer blocked
                    // behind the 8 pI MFMA issues.
                    float pf = sel4(acc[1], quad) + qp1;
                    float pi = sel4(acc[0], quad) + qp0;
                    float pg = sel4(acc[2], quad) + qp2;
                    float po = sel4(acc[3], quad) + qp3;
                    float fv = sig_p(pf), iv = sig_p(pi), ov = sig_p(po);
                    float rg = tanh_r(pg);
                    float m2iv = -2.0f * iv;
                    float igv = fmaf(m2iv, rg, iv);
                    cst = fmaf(fv, cst, igv);
                    float m2ov = -2.0f * ov;
                    float rh = tanh_r(cst * LOG2E2);
                    float hv = fmaf(m2ov, rh, ov);
                    h2a[cur][quad * HSTR + col] = (_Float16)hv;   // h2[it-2]
                    if (it == TT + 1)
                        out[(size_t)(blockIdx.x * 4 + quad) * 64 + col] = hv;
                }
                // pI(it-1) = Wih1 . h1[it-1] -> accQ[sub], AFTER the write:
                // register-only MFMAs execute during the lgkm-drain + barrier
                // wait (dead time); deadline is next iteration's qp hoist.
                if (doQ) {
                    #pragma unroll
                    for (int c = 0; c < 4; ++c) {
                        f32x4 z = Z;
                        z = __builtin_amdgcn_mfma_f32_16x16x32_f16(b0, wB[c][0], z, 0, 0, 0);
                        z = __builtin_amdgcn_mfma_f32_16x16x32_f16(b1, wB[c][1], z, 0, 0, 0);
                        accQ[sub][c] = z;
                    }
                }
            }
            lds_barrier();   // LDS-only drain; x prefetch stays in flight
        }
    }
}

extern "C" void kernel_launch(void* const* d_in, const int* in_sizes, int n_in,
                              void* d_out, int out_size, void* d_ws, size_t ws_size,
                              hipStream_t stream) {
    const float* x    = (const float*)d_in[0];
    const float* Wih0 = (const float*)d_in[1];
    const float* Whh0 = (const float*)d_in[2];
    const float* bih0 = (const float*)d_in[3];
    const float* bhh0 = (const float*)d_in[4];
    const float* Wih1 = (const float*)d_in[5];
    const float* Whh1 = (const float*)d_in[6];
    const float* bih1 = (const float*)d_in[7];
    const float* bhh1 = (const float*)d_in[8];
    float* out = (float*)d_out;

    // 512 sequences / 4 per block = 128 blocks; 512 threads (8 waves, 2/SIMD).
    lstm2_fused<<<128, 512, 0, stream>>>(x, Wih0, Whh0, bih0, bhh0,
                                         Wih1, Whh1, bih1, bhh1, out);
}

// Round 15
// 938.481 us; speedup vs baseline: 1.0242x; 1.0242x over previous
//
#include <hip/hip_runtime.h>
#include <math.h>

// BiometricLSTM: 2-layer LSTM, B=512, T=2048, I=3, H=64, fp32 in/out. Output = final h2 (B,64).
//
// R32: R30 (best, 931.2 us; R31's pI-after-write REVERTED: +3.2%, the pI issue
// was already hidden in the gate-completion wait) + ONE variable: gate order
// {f,i,g,o} -> {g,i,f,o} with matching tail order.
// Theory: the c-update fmaf(fv, cst, igv) waits on igv whose input chain
// (pg: sel4->add->exp2->add->rcp for rg, AND pi->iv->m2iv mul) is ~2 ops longer
// than fv's. Start the longest chains first: g's MFMA result lands first,
// i second, f (shorter chain) third, o (consumed last) last. Pure reorder;
// absmax 4.88e-4 canary must hold bit-exactly.
// Refuted-theories ledger: vmcnt drain (R24), x-load latency (R27), wave prio
// (R29), LDS-transported rebalance (R28), pI-after-write (R31). Model: iter
// ~454ns is the serial chain {rendezvous ~40 + ds_read ~130 + MFMA ~80 + tail
// ~100 + write/drain ~50 + loop ~20}; this round spends the last slack in it.
// R30 recap (all kept): fused tanh muls (m2iv/m2ov off-chain, fmaf on-chain);
// log2e-prescaled weights (bare v_exp2); L1 read-window sel4 hoists; 2-level
// sel4 tree; split waves L0=Whh0 8 MFMA / L1=Whh1+Wih1 16 MFMA lag-2 in order
// {reads, qp, gates, pI, tail, write}; pI in regs accQ[2][4] (write@sub,
// read@sub^1); no pIbuf; LDS 2560B, 0 conflicts; unroll-2 compile-time parity;
// M=4 replicated rows; quad-selected update; HSTR=80; z-chained MFMA pairs
// bias-in-C; x prefetch depth-1; lds_barrier (lgkmcnt-only); setprio(1) on L0;
// f16 weights/h + f32 accum.
// Parities: h1[t]@t&1; h2[t]@t&1; accQ write@sub / read@sub^1.

typedef _Float16 half8 __attribute__((ext_vector_type(8)));
typedef float    f32x4 __attribute__((ext_vector_type(4)));

constexpr int TT = 2048;
constexpr int HSTR = 80;   // h row stride in halves (160 B)

#define LOG2E  1.44269504088896340736f
#define LOG2E2 2.88539008177792681472f

// y = x*log2e applied upstream: sigmoid(x) = 1/(1+2^-y)
__device__ __forceinline__ float sig_p(float y) {
    return __builtin_amdgcn_rcpf(1.0f + __builtin_amdgcn_exp2f(-y));
}
// y = x*2log2e applied upstream: r = 1/(2^y+1); tanh(x) = 1 - 2r
__device__ __forceinline__ float tanh_r(float y) {
    return __builtin_amdgcn_rcpf(__builtin_amdgcn_exp2f(y) + 1.0f);
}
// select component q (lane's quad) from an f32x4 accumulator — 2-level tree
__device__ __forceinline__ float sel4(f32x4 v, int q) {
    float lo = (q & 1) ? v[1] : v[0];
    float hi = (q & 1) ? v[3] : v[2];
    return (q & 2) ? hi : lo;
}

// Barrier with LDS-only drain: s_waitcnt lgkmcnt(0) + s_barrier.
// Does NOT drain vmcnt — in-flight global x-prefetch loads stay in flight.
__device__ __forceinline__ void lds_barrier() {
    __builtin_amdgcn_sched_barrier(0);
    asm volatile("s_waitcnt lgkmcnt(0)" ::: "memory");
    __builtin_amdgcn_s_barrier();
    __builtin_amdgcn_sched_barrier(0);
}

__global__ __launch_bounds__(512) void lstm2_fused(
    const float* __restrict__ x,
    const float* __restrict__ Wih0, const float* __restrict__ Whh0,
    const float* __restrict__ bih0, const float* __restrict__ bhh0,
    const float* __restrict__ Wih1, const float* __restrict__ Whh1,
    const float* __restrict__ bih1, const float* __restrict__ bhh1,
    float* __restrict__ out)
{
    __shared__ __align__(16) _Float16 h1a[2][4 * HSTR];   // [parity][seq*HSTR + elem]
    __shared__ __align__(16) _Float16 h2a[2][4 * HSTR];

    const int tid  = threadIdx.x;
    const int lane = tid & 63;
    const int wid  = tid >> 6;
    const int quad = lane >> 4;
    const int l16  = lane & 15;
    const bool isL1 = (wid >= 4);
    const int col  = (wid & 3) * 16 + l16;   // gate-elem column this lane owns per class

    // ---- zero h double-buffers ----
    for (int i = tid; i < 2 * 4 * HSTR; i += 512) {
        ((_Float16*)h1a)[i] = (_Float16)0.0f;
        ((_Float16*)h2a)[i] = (_Float16)0.0f;
    }

    // ---- weights (B-frags, f16), log2e-prescaled per gate class ----
    // class c: 0=i 1=f 2=g 3=o; scale = log2e (sigmoid) or 2*log2e (tanh g)
    half8 wA[4][2];      // L0 waves: Whh0 | L1 waves: Whh1
    half8 wB[4][2];      // L1 waves only: Wih1
    f32x4 cbias[4];      // bias splat (prescaled), MFMA C-init
    float wxa[4], wxb[4], wxc[4];            // L0 only (prescaled)
    #pragma unroll
    for (int c = 0; c < 4; ++c) {
        const int row = c * 64 + col;
        const float sc = (c == 2) ? LOG2E2 : LOG2E;
        if (!isL1) {
            #pragma unroll
            for (int f = 0; f < 2; ++f) {
                const float* p = Whh0 + (size_t)row * 64 + f * 32 + quad * 8;
                half8 h;
                #pragma unroll
                for (int u = 0; u < 8; ++u) h[u] = (_Float16)(p[u] * sc);
                wA[c][f] = h;
            }
            const float b = (bih0[row] + bhh0[row]) * sc;
            cbias[c] = f32x4{b, b, b, b};
            wxa[c] = Wih0[row*3+0] * sc;
            wxb[c] = Wih0[row*3+1] * sc;
            wxc[c] = Wih0[row*3+2] * sc;
        } else {
            #pragma unroll
            for (int f = 0; f < 2; ++f) {
                const float* p = Whh1 + (size_t)row * 64 + f * 32 + quad * 8;
                half8 h;
                #pragma unroll
                for (int u = 0; u < 8; ++u) h[u] = (_Float16)(p[u] * sc);
                wA[c][f] = h;
                const float* q = Wih1 + (size_t)row * 64 + f * 32 + quad * 8;
                half8 g;
                #pragma unroll
                for (int u = 0; u < 8; ++u) g[u] = (_Float16)(q[u] * sc);
                wB[c][f] = g;
            }
            const float b = (bih1[row] + bhh1[row]) * sc;
            cbias[c] = f32x4{b, b, b, b};
        }
    }

    // ---- x prefetch (L0 waves), depth 1: this lane's seq = quad ----
    const float* xq = x + (size_t)(blockIdx.x * 4 + quad) * TT * 3;
    float xn0 = 0.f, xn1 = 0.f, xn2 = 0.f;
    if (!isL1) { xn0 = xq[0]; xn1 = xq[1]; xn2 = xq[2]; }

    const f32x4 Z = {0.f, 0.f, 0.f, 0.f};
    float cst = 0.0f;    // cell state (layer per role, seq=quad, elem=col)

    // L1: pI double-buffer in registers; accQ[sub] written at parity sub,
    // read at sub^1. Indices are compile-time after the unroll (rule #20).
    f32x4 accQ[2][4];
    #pragma unroll
    for (int s = 0; s < 2; ++s)
        #pragma unroll
        for (int c = 0; c < 4; ++c) accQ[s][c] = Z;

    // protect the h1-recurrence wave at issue-contention points (R29: neutral,
    // kept — no cost).
    if (!isL1) __builtin_amdgcn_s_setprio(1);

    __syncthreads();   // init barrier: full drain fine here (once)

    // MFMA issue order: g first (longest post-MFMA chain into the c-fma:
    // sel->add->exp2->add->rcp AND the iv->m2iv mul), i second, f third
    // (2 ops shorter), o last (consumed last).
    const int ORD[4] = {2, 0, 1, 3};

    // iter it = 0 .. TT+1 in unrolled pairs (cur/prev compile-time).
    // L0: step it (it<TT).  L1: gates for step it-2 (it>=2) + pI(it-1) (1<=it<=TT).
    // ONE lds_barrier per iteration.
    for (int bt = 0; bt <= TT + 1; bt += 2) {
        #pragma unroll
        for (int sub = 0; sub < 2; ++sub) {
            const int it   = bt + sub;
            const int cur  = sub;        // bt even => it&1 == sub
            const int prev = sub ^ 1;

            if (!isL1) {
                if (it < TT) {
                    // A-frags: h1[it-1] (parity prev), replicated rows
                    const _Float16* hb = h1a[prev] + (l16 & 3) * HSTR + quad * 8;
                    half8 a0 = *(const half8*)hb;
                    half8 a1 = *(const half8*)(hb + 32);

                    // x-projection (prescaled): fills the ds_read window.
                    const float x0 = xn0, x1 = xn1, x2 = xn2;
                    float xp0 = fmaf(wxa[0], x0, fmaf(wxb[0], x1, wxc[0] * x2));
                    float xp1 = fmaf(wxa[1], x0, fmaf(wxb[1], x1, wxc[1] * x2));
                    float xp2 = fmaf(wxa[2], x0, fmaf(wxb[2], x1, wxc[2] * x2));
                    float xp3 = fmaf(wxa[3], x0, fmaf(wxb[3], x1, wxc[3] * x2));
                    const int nt = (it + 1 < TT) ? it + 1 : TT - 1;
                    const float* np = xq + nt * 3;
                    xn0 = np[0]; xn1 = np[1]; xn2 = np[2];

                    // L0 gates: Whh0 . h1[it-1] + bias (in C), g-class first.
                    f32x4 acc[4];
                    #pragma unroll
                    for (int k = 0; k < 4; ++k) {
                        const int c = ORD[k];
                        f32x4 z = cbias[c];
                        z = __builtin_amdgcn_mfma_f32_16x16x32_f16(a0, wA[c][0], z, 0, 0, 0);
                        z = __builtin_amdgcn_mfma_f32_16x16x32_f16(a1, wA[c][1], z, 0, 0, 0);
                        acc[c] = z;
                    }
                    // tail in chain-length order: g, i, f, o
                    float pg = sel4(acc[2], quad) + xp2;
                    float pi = sel4(acc[0], quad) + xp0;
                    float pf = sel4(acc[1], quad) + xp1;
                    float po = sel4(acc[3], quad) + xp3;
                    float rg = tanh_r(pg);
                    float iv = sig_p(pi);
                    float fv = sig_p(pf), ov = sig_p(po);
                    float m2iv = -2.0f * iv;                 // off-chain
                    float igv = fmaf(m2iv, rg, iv);          // iv*tanh(g), 1 dep
                    cst = fmaf(fv, cst, igv);
                    float m2ov = -2.0f * ov;                 // off-chain (c runs)
                    float rh = tanh_r(cst * LOG2E2);
                    float hv = fmaf(m2ov, rh, ov);           // ov*tanh(c), 1 dep
                    h1a[cur][quad * HSTR + col] = (_Float16)hv;   // h1[it]
                }
            } else {
                const bool doG = (it >= 2);             // gates for step it-2
                const bool doQ = (it >= 1 && it <= TT); // pI(it-1) for next iter

                // ds_reads first (both frag sets issue together)
                half8 a2, a3, b0, b1;
                if (doG) {
                    const _Float16* hb2 = h2a[prev] + (l16 & 3) * HSTR + quad * 8;
                    a2 = *(const half8*)hb2;
                    a3 = *(const half8*)(hb2 + 32);
                }
                if (doQ) {
                    const _Float16* hb1 = h1a[prev] + (l16 & 3) * HSTR + quad * 8;
                    b0 = *(const half8*)hb1;
                    b1 = *(const half8*)(hb1 + 32);
                }

                // read-window fill: pI(it-2) quad-selects (off the tail chain)
                float qp0, qp1, qp2, qp3;
                if (doG) {
                    qp0 = sel4(accQ[prev][0], quad);
                    qp1 = sel4(accQ[prev][1], quad);
                    qp2 = sel4(accQ[prev][2], quad);
                    qp3 = sel4(accQ[prev][3], quad);
                }

                // CRITICAL: gate MFMAs issue first, g-class first (R30 body
                // order restored: gates -> pI -> tail -> write).
                f32x4 acc[4];
                if (doG) {
                    #pragma unroll
                    for (int k = 0; k < 4; ++k) {
                        const int c = ORD[k];
                        f32x4 z = cbias[c];
                        z = __builtin_amdgcn_mfma_f32_16x16x32_f16(a2, wA[c][0], z, 0, 0, 0);
                        z = __builtin_amdgcn_mfma_f32_16x16x32_f16(a3, wA[c][1], z, 0, 0, 0);
                        acc[c] = z;
                    }
                }
                // pI(it-1) = Wih1 . h1[it-1] -> accQ[sub] (registers, consumed
                // NEXT iteration). Issues behind gates; executes under the
                // tail's acc-completion wait (R31 proved this hiding is real).
                if (doQ) {
                    #pragma unroll
                    for (int c = 0; c < 4; ++c) {
                        f32x4 z = Z;
                        z = __builtin_amdgcn_mfma_f32_16x16x32_f16(b0, wB[c][0], z, 0, 0, 0);
                        z = __builtin_amdgcn_mfma_f32_16x16x32_f16(b1, wB[c][1], z, 0, 0, 0);
                        accQ[sub][c] = z;
                    }
                }

                if (doG) {
                    // gates = Whh1.h2[it-3] + bias + pI(it-2); tail g,i,f,o
                    float pg = sel4(acc[2], quad) + qp2;
                    float pi = sel4(acc[0], quad) + qp0;
                    float pf = sel4(acc[1], quad) + qp1;
                    float po = sel4(acc[3], quad) + qp3;
                    float rg = tanh_r(pg);
                    float iv = sig_p(pi);
                    float fv = sig_p(pf), ov = sig_p(po);
                    float m2iv = -2.0f * iv;
                    float igv = fmaf(m2iv, rg, iv);
                    cst = fmaf(fv, cst, igv);
                    float m2ov = -2.0f * ov;
                    float rh = tanh_r(cst * LOG2E2);
                    float hv = fmaf(m2ov, rh, ov);
                    h2a[cur][quad * HSTR + col] = (_Float16)hv;   // h2[it-2]
                    if (it == TT + 1)
                        out[(size_t)(blockIdx.x * 4 + quad) * 64 + col] = hv;
                }
            }
            lds_barrier();   // LDS-only drain; x prefetch stays in flight
        }
    }
}

extern "C" void kernel_launch(void* const* d_in, const int* in_sizes, int n_in,
                              void* d_out, int out_size, void* d_ws, size_t ws_size,
                              hipStream_t stream) {
    const float* x    = (const float*)d_in[0];
    const float* Wih0 = (const float*)d_in[1];
    const float* Whh0 = (const float*)d_in[2];
    const float* bih0 = (const float*)d_in[3];
    const float* bhh0 = (const float*)d_in[4];
    const float* Wih1 = (const float*)d_in[5];
    const float* Whh1 = (const float*)d_in[6];
    const float* bih1 = (const float*)d_in[7];
    const float* bhh1 = (const float*)d_in[8];
    float* out = (float*)d_out;

    // 512 sequences / 4 per block = 128 blocks; 512 threads (8 waves, 2/SIMD).
    lstm2_fused<<<128, 512, 0, stream>>>(x, Wih0, Whh0, bih0, bhh0,
                                         Wih1, Whh1, bih1, bhh1, out);
}

// Round 16
// 829.402 us; speedup vs baseline: 1.1589x; 1.1315x over previous
//
#include <hip/hip_runtime.h>
#include <math.h>

// BiometricLSTM: 2-layer LSTM, B=512, T=2048, I=3, H=64, fp32 in/out. Output = final h2 (B,64).
//
// R33: R32 (938.5 us; R30 931.2 — statistically equal) + ONE variable:
// quad-replication layout change that ELIMINATES every sel4.
// C/D layout (m89, dtype-independent): col=lane&15, row=(lane>>4)*4+reg, so
// lane in quad q holds rows 4q..4q+3 in regs 0..3. Old A-replication put
// seq = row&3 (read offset (l16&3)*HSTR) -> reg j = seq j -> per-gate sel4
// (2 serial cndmasks on the chain; 12/role/step). New: seq = row>>2 (read
// offset (l16>>2)*HSTR) -> all 4 regs of lane q hold seq q -> wanted value is
// acc[c][0] directly. qp hoists become register reads (free). Same dot
// products, bit-identical arithmetic -> absmax 4.88e-4 canary must hold.
// Bank check: same 16 distinct b128 addresses, 4-lane broadcast, uniform
// 2-way (free, m136) — unchanged.
// Refuted ledger: vmcnt drain (R24), x latency (R27), prio (R29), LDS
// rebalance (R28), pI-after-write (R31), gate-order g-first (R32 neutral).
// R30/R32 recap (all kept): fused tanh muls (m2iv/m2ov off-chain); log2e-
// prescaled weights (bare v_exp2); split waves L0=Whh0 8 MFMA / L1=Whh1+Wih1
// 16 MFMA lag-2 in order {reads, qp, gates, pI, tail, write}; pI in regs
// accQ[2][4] (write@sub, read@sub^1); no pIbuf; LDS 2560B, 0 conflicts;
// unroll-2 compile-time parity; M=4 replicated rows (NEW pattern seq=row>>2);
// HSTR=80; z-chained MFMA pairs bias-in-C; x prefetch depth-1; lds_barrier
// (lgkmcnt-only); setprio(1) on L0; f16 weights/h + f32 accum.
// Parities: h1[t]@t&1; h2[t]@t&1; accQ write@sub / read@sub^1.

typedef _Float16 half8 __attribute__((ext_vector_type(8)));
typedef float    f32x4 __attribute__((ext_vector_type(4)));

constexpr int TT = 2048;
constexpr int HSTR = 80;   // h row stride in halves (160 B)

#define LOG2E  1.44269504088896340736f
#define LOG2E2 2.88539008177792681472f

// y = x*log2e applied upstream: sigmoid(x) = 1/(1+2^-y)
__device__ __forceinline__ float sig_p(float y) {
    return __builtin_amdgcn_rcpf(1.0f + __builtin_amdgcn_exp2f(-y));
}
// y = x*2log2e applied upstream: r = 1/(2^y+1); tanh(x) = 1 - 2r
__device__ __forceinline__ float tanh_r(float y) {
    return __builtin_amdgcn_rcpf(__builtin_amdgcn_exp2f(y) + 1.0f);
}

// Barrier with LDS-only drain: s_waitcnt lgkmcnt(0) + s_barrier.
// Does NOT drain vmcnt — in-flight global x-prefetch loads stay in flight.
__device__ __forceinline__ void lds_barrier() {
    __builtin_amdgcn_sched_barrier(0);
    asm volatile("s_waitcnt lgkmcnt(0)" ::: "memory");
    __builtin_amdgcn_s_barrier();
    __builtin_amdgcn_sched_barrier(0);
}

__global__ __launch_bounds__(512) void lstm2_fused(
    const float* __restrict__ x,
    const float* __restrict__ Wih0, const float* __restrict__ Whh0,
    const float* __restrict__ bih0, const float* __restrict__ bhh0,
    const float* __restrict__ Wih1, const float* __restrict__ Whh1,
    const float* __restrict__ bih1, const float* __restrict__ bhh1,
    float* __restrict__ out)
{
    __shared__ __align__(16) _Float16 h1a[2][4 * HSTR];   // [parity][seq*HSTR + elem]
    __shared__ __align__(16) _Float16 h2a[2][4 * HSTR];

    const int tid  = threadIdx.x;
    const int lane = tid & 63;
    const int wid  = tid >> 6;
    const int quad = lane >> 4;
    const int l16  = lane & 15;
    const bool isL1 = (wid >= 4);
    const int col  = (wid & 3) * 16 + l16;   // gate-elem column this lane owns per class

    // ---- zero h double-buffers ----
    for (int i = tid; i < 2 * 4 * HSTR; i += 512) {
        ((_Float16*)h1a)[i] = (_Float16)0.0f;
        ((_Float16*)h2a)[i] = (_Float16)0.0f;
    }

    // ---- weights (B-frags, f16), log2e-prescaled per gate class ----
    // class c: 0=i 1=f 2=g 3=o; scale = log2e (sigmoid) or 2*log2e (tanh g)
    half8 wA[4][2];      // L0 waves: Whh0 | L1 waves: Whh1
    half8 wB[4][2];      // L1 waves only: Wih1
    f32x4 cbias[4];      // bias splat (prescaled), MFMA C-init
    float wxa[4], wxb[4], wxc[4];            // L0 only (prescaled)
    #pragma unroll
    for (int c = 0; c < 4; ++c) {
        const int row = c * 64 + col;
        const float sc = (c == 2) ? LOG2E2 : LOG2E;
        if (!isL1) {
            #pragma unroll
            for (int f = 0; f < 2; ++f) {
                const float* p = Whh0 + (size_t)row * 64 + f * 32 + quad * 8;
                half8 h;
                #pragma unroll
                for (int u = 0; u < 8; ++u) h[u] = (_Float16)(p[u] * sc);
                wA[c][f] = h;
            }
            const float b = (bih0[row] + bhh0[row]) * sc;
            cbias[c] = f32x4{b, b, b, b};
            wxa[c] = Wih0[row*3+0] * sc;
            wxb[c] = Wih0[row*3+1] * sc;
            wxc[c] = Wih0[row*3+2] * sc;
        } else {
            #pragma unroll
            for (int f = 0; f < 2; ++f) {
                const float* p = Whh1 + (size_t)row * 64 + f * 32 + quad * 8;
                half8 h;
                #pragma unroll
                for (int u = 0; u < 8; ++u) h[u] = (_Float16)(p[u] * sc);
                wA[c][f] = h;
                const float* q = Wih1 + (size_t)row * 64 + f * 32 + quad * 8;
                half8 g;
                #pragma unroll
                for (int u = 0; u < 8; ++u) g[u] = (_Float16)(q[u] * sc);
                wB[c][f] = g;
            }
            const float b = (bih1[row] + bhh1[row]) * sc;
            cbias[c] = f32x4{b, b, b, b};
        }
    }

    // ---- x prefetch (L0 waves), depth 1: this lane's seq = quad ----
    const float* xq = x + (size_t)(blockIdx.x * 4 + quad) * TT * 3;
    float xn0 = 0.f, xn1 = 0.f, xn2 = 0.f;
    if (!isL1) { xn0 = xq[0]; xn1 = xq[1]; xn2 = xq[2]; }

    const f32x4 Z = {0.f, 0.f, 0.f, 0.f};
    float cst = 0.0f;    // cell state (layer per role, seq=quad, elem=col)

    // L1: pI double-buffer in registers; accQ[sub] written at parity sub,
    // read at sub^1. Indices are compile-time after the unroll (rule #20).
    f32x4 accQ[2][4];
    #pragma unroll
    for (int s = 0; s < 2; ++s)
        #pragma unroll
        for (int c = 0; c < 4; ++c) accQ[s][c] = Z;

    // protect the h1-recurrence wave at issue-contention points (R29: neutral,
    // kept — no cost).
    if (!isL1) __builtin_amdgcn_s_setprio(1);

    __syncthreads();   // init barrier: full drain fine here (once)

    // MFMA issue order: g first (longest post-MFMA chain), i, f, o.
    const int ORD[4] = {2, 0, 1, 3};

    // iter it = 0 .. TT+1 in unrolled pairs (cur/prev compile-time).
    // L0: step it (it<TT).  L1: gates for step it-2 (it>=2) + pI(it-1) (1<=it<=TT).
    // ONE lds_barrier per iteration.
    for (int bt = 0; bt <= TT + 1; bt += 2) {
        #pragma unroll
        for (int sub = 0; sub < 2; ++sub) {
            const int it   = bt + sub;
            const int cur  = sub;        // bt even => it&1 == sub
            const int prev = sub ^ 1;

            if (!isL1) {
                if (it < TT) {
                    // A-frags: h1[it-1] (parity prev). NEW replication
                    // seq = row>>2: A row r (lane l16) reads seq l16>>2, so
                    // C/D rows 4q..4q+3 all hold seq q -> acc[c][0] direct.
                    const _Float16* hb = h1a[prev] + (l16 >> 2) * HSTR + quad * 8;
                    half8 a0 = *(const half8*)hb;
                    half8 a1 = *(const half8*)(hb + 32);

                    // x-projection (prescaled): fills the ds_read window.
                    const float x0 = xn0, x1 = xn1, x2 = xn2;
                    float xp0 = fmaf(wxa[0], x0, fmaf(wxb[0], x1, wxc[0] * x2));
                    float xp1 = fmaf(wxa[1], x0, fmaf(wxb[1], x1, wxc[1] * x2));
                    float xp2 = fmaf(wxa[2], x0, fmaf(wxb[2], x1, wxc[2] * x2));
                    float xp3 = fmaf(wxa[3], x0, fmaf(wxb[3], x1, wxc[3] * x2));
                    const int nt = (it + 1 < TT) ? it + 1 : TT - 1;
                    const float* np = xq + nt * 3;
                    xn0 = np[0]; xn1 = np[1]; xn2 = np[2];

                    // L0 gates: Whh0 . h1[it-1] + bias (in C), g-class first.
                    f32x4 acc[4];
                    #pragma unroll
                    for (int k = 0; k < 4; ++k) {
                        const int c = ORD[k];
                        f32x4 z = cbias[c];
                        z = __builtin_amdgcn_mfma_f32_16x16x32_f16(a0, wA[c][0], z, 0, 0, 0);
                        z = __builtin_amdgcn_mfma_f32_16x16x32_f16(a1, wA[c][1], z, 0, 0, 0);
                        acc[c] = z;
                    }
                    // tail: no sel4 — reg 0 is this lane's (seq=quad, col).
                    float pg = acc[2][0] + xp2;
                    float pi = acc[0][0] + xp0;
                    float pf = acc[1][0] + xp1;
                    float po = acc[3][0] + xp3;
                    float rg = tanh_r(pg);
                    float iv = sig_p(pi);
                    float fv = sig_p(pf), ov = sig_p(po);
                    float m2iv = -2.0f * iv;                 // off-chain
                    float igv = fmaf(m2iv, rg, iv);          // iv*tanh(g), 1 dep
                    cst = fmaf(fv, cst, igv);
                    float m2ov = -2.0f * ov;                 // off-chain (c runs)
                    float rh = tanh_r(cst * LOG2E2);
                    float hv = fmaf(m2ov, rh, ov);           // ov*tanh(c), 1 dep
                    h1a[cur][quad * HSTR + col] = (_Float16)hv;   // h1[it]
                }
            } else {
                const bool doG = (it >= 2);             // gates for step it-2
                const bool doQ = (it >= 1 && it <= TT); // pI(it-1) for next iter

                // ds_reads first (both frag sets issue together); NEW
                // replication seq = row>>2 on both frag sets.
                half8 a2, a3, b0, b1;
                if (doG) {
                    const _Float16* hb2 = h2a[prev] + (l16 >> 2) * HSTR + quad * 8;
                    a2 = *(const half8*)hb2;
                    a3 = *(const half8*)(hb2 + 32);
                }
                if (doQ) {
                    const _Float16* hb1 = h1a[prev] + (l16 >> 2) * HSTR + quad * 8;
                    b0 = *(const half8*)hb1;
                    b1 = *(const half8*)(hb1 + 32);
                }

                // pI(it-2) partials: plain register reads now (reg 0).
                float qp0, qp1, qp2, qp3;
                if (doG) {
                    qp0 = accQ[prev][0][0];
                    qp1 = accQ[prev][1][0];
                    qp2 = accQ[prev][2][0];
                    qp3 = accQ[prev][3][0];
                }

                // CRITICAL: gate MFMAs issue first, g-class first
                // (order: gates -> pI -> tail -> write).
                f32x4 acc[4];
                if (doG) {
                    #pragma unroll
                    for (int k = 0; k < 4; ++k) {
                        const int c = ORD[k];
                        f32x4 z = cbias[c];
                        z = __builtin_amdgcn_mfma_f32_16x16x32_f16(a2, wA[c][0], z, 0, 0, 0);
                        z = __builtin_amdgcn_mfma_f32_16x16x32_f16(a3, wA[c][1], z, 0, 0, 0);
                        acc[c] = z;
                    }
                }
                // pI(it-1) = Wih1 . h1[it-1] -> accQ[sub] (registers, consumed
                // NEXT iteration). Issues behind gates; executes under the
                // tail's acc-completion wait (R31 proved this hiding is real).
                if (doQ) {
                    #pragma unroll
                    for (int c = 0; c < 4; ++c) {
                        f32x4 z = Z;
                        z = __builtin_amdgcn_mfma_f32_16x16x32_f16(b0, wB[c][0], z, 0, 0, 0);
                        z = __builtin_amdgcn_mfma_f32_16x16x32_f16(b1, wB[c][1], z, 0, 0, 0);
                        accQ[sub][c] = z;
                    }
                }

                if (doG) {
                    // gates = Whh1.h2[it-3] + bias + pI(it-2); no sel4.
                    float pg = acc[2][0] + qp2;
                    float pi = acc[0][0] + qp0;
                    float pf = acc[1][0] + qp1;
                    float po = acc[3][0] + qp3;
                    float rg = tanh_r(pg);
                    float iv = sig_p(pi);
                    float fv = sig_p(pf), ov = sig_p(po);
                    float m2iv = -2.0f * iv;
                    float igv = fmaf(m2iv, rg, iv);
                    cst = fmaf(fv, cst, igv);
                    float m2ov = -2.0f * ov;
                    float rh = tanh_r(cst * LOG2E2);
                    float hv = fmaf(m2ov, rh, ov);
                    h2a[cur][quad * HSTR + col] = (_Float16)hv;   // h2[it-2]
                    if (it == TT + 1)
                        out[(size_t)(blockIdx.x * 4 + quad) * 64 + col] = hv;
                }
            }
            lds_barrier();   // LDS-only drain; x prefetch stays in flight
        }
    }
}

extern "C" void kernel_launch(void* const* d_in, const int* in_sizes, int n_in,
                              void* d_out, int out_size, void* d_ws, size_t ws_size,
                              hipStream_t stream) {
    const float* x    = (const float*)d_in[0];
    const float* Wih0 = (const float*)d_in[1];
    const float* Whh0 = (const float*)d_in[2];
    const float* bih0 = (const float*)d_in[3];
    const float* bhh0 = (const float*)d_in[4];
    const float* Wih1 = (const float*)d_in[5];
    const float* Whh1 = (const float*)d_in[6];
    const float* bih1 = (const float*)d_in[7];
    const float* bhh1 = (const float*)d_in[8];
    float* out = (float*)d_out;

    // 512 sequences / 4 per block = 128 blocks; 512 threads (8 waves, 2/SIMD).
    lstm2_fused<<<128, 512, 0, stream>>>(x, Wih0, Whh0, bih0, bhh0,
                                         Wih1, Whh1, bih1, bhh1, out);
}